// Round 11
// baseline (939.909 us; speedup 1.0000x reference)
//
#include <hip/hip_runtime.h>
#include <math.h>

// ---------------- problem constants ----------------
#define BB    8
#define HH    128
#define WW    128
#define DIM   96
#define MED   192
#define HWPX  16384        // H*W
#define PSTR  16672        // padded P plane stride (floats): 66688 B = 128*521
#define FWH   65
#define LSTR  67           // spectral LDS row stride in float2 units

#define PW1_GRID 4096      // 32 px per block (split-tile pw1)

// workspace layout (float offsets)
#define P_OFF     0
#define P_SZ      (8*192*PSTR)             // x_pre / xsp planes [b][m][PSTR]
#define FILT_OFF  (P_OFF + P_SZ)
#define FILT_SZ   (3*192*128*65*2)         // filt [s][m][fh][fw] complex (NATURAL layout)
#define PART_OFF  (FILT_OFF + FILT_SZ)     // pw1 routing partials [b][144][512]
#define PART_SZ   (8*144*512)
#define R_OFF     (PART_OFF + PART_SZ)     // r  8*3*192
#define W1B_OFF   (R_OFF + 4608)           // 46080 ushort = 23040 float slots
#define W2B_OFF   (W1B_OFF + 23040)        // 36864 ushort = 18432 float slots
#define CNT_OFF   (W2B_OFF + 18432)        // completion counter (1 int)

typedef __attribute__((ext_vector_type(8))) short short8_t;
typedef __attribute__((ext_vector_type(4))) float float4_t;

__device__ __forceinline__ unsigned short bf16_rne(float f){
  unsigned u = __float_as_uint(f);
  unsigned r = (u + 0x7FFFu + ((u>>16)&1u)) >> 16;
  return (unsigned short)r;
}
__device__ __forceinline__ float bf16_to_f(unsigned short h){
  return __uint_as_float(((unsigned)h) << 16);
}

// =====================================================================
// K_prep_filt: FUSED independent preprocessing.
//  blocks 0..35   : pack [w1 ; sp_w] and w2 into MFMA fragment order
//  blocks 36..611 : separable bicubic filter resize
//  block 0 thread 0 also zeroes the pw1 completion counter.
// =====================================================================
__device__ __forceinline__ float cubicw(float tt){
  float t = fabsf(tt), t2=t*t, t3=t2*t;
  if (t <= 1.f) return 1.25f*t3 - 2.25f*t2 + 1.f;
  if (t < 2.f)  return -0.75f*t3 + 3.75f*t2 - 6.f*t + 3.f;
  return 0.f;
}

__global__ __launch_bounds__(256) void k_prep_filt(
    const float* __restrict__ w1, const float* __restrict__ sp_w,
    const float* __restrict__ w2,
    const float* __restrict__ cw0, const float* __restrict__ cw1,
    const float* __restrict__ cw2,
    unsigned short* __restrict__ W1B, unsigned short* __restrict__ W2B,
    float* __restrict__ filt, int* __restrict__ cnt)
{
  __shared__ float2 T[128][13];
  int bx = blockIdx.x;
  int t = threadIdx.x;

  if (bx < 36) {
    if (bx == 0 && t == 0) *cnt = 0;      // reset pw1 completion counter
    int tid = t + bx*256;
    int nthr = 256*36;
    for (int i = tid; i < 2*3*15*512; i += nthr) {
      int j = i & 7, l = (i>>3) & 63;
      int nt = (i>>9) % 15, kc = ((i>>9)/15) % 3, term = i / (3*15*512);
      int r = nt*16 + (l&15);
      int c = kc*32 + (l>>4)*8 + j;
      float v = (r < 192) ? w1[r*96 + c] : sp_w[(r-192)*96 + c];
      unsigned short hi = bf16_rne(v);
      W1B[i] = (term==0) ? hi : bf16_rne(v - bf16_to_f(hi));
    }
    for (int i = tid; i < 2*6*6*512; i += nthr) {
      int j = i & 7, l = (i>>3) & 63;
      int nt = (i>>9) % 6, kc = ((i>>9)/6) % 6, term = i / (6*6*512);
      int cp = nt*16 + (l&15);
      int m  = kc*32 + (l>>4)*8 + j;
      float v = w2[cp*192 + m];
      unsigned short hi = bf16_rne(v);
      W2B[i] = (term==0) ? hi : bf16_rne(v - bf16_to_f(hi));
    }
    return;
  }

  int fb = bx - 36;
  int s = fb / 192, m = fb - s*192;
  const float* cw = (s==0) ? cw0 : ((s==1) ? cw1 : cw2);
  const int SH = (s==0) ? 16 : ((s==1) ? 8 : 24);
  const int SW = (s==0) ? 9  : ((s==1) ? 4 : 13);

  for (int i = t; i < 128*SW; i += 256) {
    int fh = i / SW, iw = i - fh*SW;
    float sh = fh * (float)(SH-1) / 127.f;
    int fh0 = (int)floorf(sh);
    float2 acc = make_float2(0.f, 0.f);
    #pragma unroll
    for (int ka=0; ka<4; ++ka) {
      int kk = fh0-1+ka;
      float w = cubicw(sh - (float)kk);
      int ih = min(max(kk,0), SH-1);
      float2 v = *(const float2*)(cw + (size_t)((ih*SW + iw)*192 + m)*2);
      acc.x = fmaf(w, v.x, acc.x);
      acc.y = fmaf(w, v.y, acc.y);
    }
    T[fh][iw] = acc;
  }
  __syncthreads();

  float2* outp = (float2*)filt + (size_t)(s*192+m)*8320;
  for (int i = t; i < 128*65; i += 256) {
    int fh = i / 65, fw = i - fh*65;
    float sw = fw * (float)(SW-1) / 64.f;
    int fw0 = (int)floorf(sw);
    float2 acc = make_float2(0.f, 0.f);
    #pragma unroll
    for (int kb=0; kb<4; ++kb) {
      int jj = fw0-1+kb;
      float w = cubicw(sw - (float)jj);
      int iw = min(max(jj,0), SW-1);
      float2 v = T[fh][iw];
      acc.x = fmaf(w, v.x, acc.x);
      acc.y = fmaf(w, v.y, acc.y);
    }
    outp[i] = acc;
  }
}

// =====================================================================
// K_pw1 v4 (split-tile + fused routing):
//  r7 counters (v2): Mfma 9.5 / VALU 16 / HBM 25 / Occ 26 — nothing
//  saturated => latency-bound; acc[15]=60 AGPRs caps ~3 waves/SIMD.
//  Fix: split the 15 output tiles across wave PAIRS.  Block = 32 px,
//  4 waves: (pg = wv>>1) px-group, (h = wv&1) tile-half.  acc: 8 tiles
//  = 32 AGPRs/wave -> ~5 waves/SIMD.  Grid 4096.  Same total work.
//  Routing MLP+softmax fused via last-block completion counter: the
//  final 8 blocks each route one batch (saves the k_route2 launch).
// =====================================================================
__global__ __launch_bounds__(256) void k_pw1(
    const float* __restrict__ x, const unsigned short* __restrict__ W1B,
    const float* __restrict__ soa_scale, const float* __restrict__ soa_bias,
    const float* __restrict__ bn_gamma, const float* __restrict__ bn_beta,
    const float* __restrict__ bn_mean, const float* __restrict__ bn_var,
    float* __restrict__ P, float* __restrict__ part, int* __restrict__ cnt,
    const float* __restrict__ fc1, const float* __restrict__ fc2,
    const float* __restrict__ mlp_scale, const float* __restrict__ mlp_bias,
    float* __restrict__ r_out)
{
  __shared__ float red[2][144];
  __shared__ float bnA_s[48], bnB_s[48];
  int t = threadIdx.x;
  int lane = t & 63, wv = t >> 6;
  int pg = wv >> 1, h = wv & 1;
  if (t < 48) {
    float a = bn_gamma[t] * rsqrtf(bn_var[t] + 1e-5f);
    bnA_s[t] = a; bnB_s[t] = bn_beta[t] - bn_mean[t]*a;
  }
  int blk = blockIdx.x;
  int px0 = blk*32 + pg*16;
  int b = (blk*32) >> 14;
  int pxl = px0 & 16383;
  int g = lane >> 4;

  float4_t acc[8];
  #pragma unroll
  for (int nt=0; nt<8; ++nt) acc[nt] = (float4_t){0.f,0.f,0.f,0.f};

  #pragma unroll
  for (int kc=0; kc<3; ++kc) {
    const float* xp = x + (size_t)(px0 + (lane&15))*96 + kc*32 + g*8;
    float4 v0 = *(const float4*)xp;
    float4 v1 = *(const float4*)(xp+4);
    float vv[8] = {v0.x,v0.y,v0.z,v0.w, v1.x,v1.y,v1.z,v1.w};
    if (h == 0) {            // gctx partial: computed once per px-group
      #pragma unroll
      for (int j=0;j<8;j++){
        float s = vv[j];
        s += __shfl_xor(s, 1);
        s += __shfl_xor(s, 2);
        s += __shfl_xor(s, 4);
        s += __shfl_xor(s, 8);
        if ((lane & 15) == 0) red[pg][kc*32 + g*8 + j] = s;
      }
    }
    short8_t Bh, Bl;
    #pragma unroll
    for (int j=0;j<8;j++){
      unsigned short hh = bf16_rne(vv[j]);
      Bh[j] = (short)hh;
      Bl[j] = (short)bf16_rne(vv[j] - bf16_to_f(hh));
    }
    const short8_t* a_hi = (const short8_t*)(W1B + (size_t)(0*3+kc)*15*512) + lane;
    const short8_t* a_lo = (const short8_t*)(W1B + (size_t)(1*3+kc)*15*512) + lane;
    if (h == 0) {
      #pragma unroll
      for (int nt=0; nt<8; ++nt) {
        short8_t Ah = a_hi[nt*64];
        short8_t Al = a_lo[nt*64];
        acc[nt] = __builtin_amdgcn_mfma_f32_16x16x32_bf16(Ah, Bh, acc[nt], 0,0,0);
        acc[nt] = __builtin_amdgcn_mfma_f32_16x16x32_bf16(Ah, Bl, acc[nt], 0,0,0);
        acc[nt] = __builtin_amdgcn_mfma_f32_16x16x32_bf16(Al, Bh, acc[nt], 0,0,0);
      }
    } else {
      #pragma unroll
      for (int nt=0; nt<7; ++nt) {
        short8_t Ah = a_hi[(nt+8)*64];
        short8_t Al = a_lo[(nt+8)*64];
        acc[nt] = __builtin_amdgcn_mfma_f32_16x16x32_bf16(Ah, Bh, acc[nt], 0,0,0);
        acc[nt] = __builtin_amdgcn_mfma_f32_16x16x32_bf16(Ah, Bl, acc[nt], 0,0,0);
        acc[nt] = __builtin_amdgcn_mfma_f32_16x16x32_bf16(Al, Bh, acc[nt], 0,0,0);
      }
    }
  }
  float sc = soa_scale[0], bi = soa_bias[0];
  if (h == 0) {
    // tiles 0..7 -> P planes 0..127
    #pragma unroll
    for (int nt=0; nt<8; ++nt) {
      #pragma unroll
      for (int q=0;q<4;q++){
        float d = acc[nt][q];
        float v = fmaxf(d, 0.f);
        d = sc*v*v + bi;
        int mp = nt*16 + g*4 + q;
        P[(size_t)(b*192 + mp)*PSTR + pxl + (lane&15)] = d;
      }
    }
  } else {
    // tiles 8..11 -> P planes 128..191
    #pragma unroll
    for (int nt=0; nt<4; ++nt) {
      #pragma unroll
      for (int q=0;q<4;q++){
        float d = acc[nt][q];
        float v = fmaxf(d, 0.f);
        d = sc*v*v + bi;
        int mp = (nt+8)*16 + g*4 + q;
        P[(size_t)(b*192 + mp)*PSTR + pxl + (lane&15)] = d;
      }
    }
    // tiles 12..14 -> sctx (BN + relu + px-sum)
    #pragma unroll
    for (int tile=0; tile<3; ++tile) {
      #pragma unroll
      for (int q=0;q<4;q++){
        int s = tile*16 + g*4 + q;
        float y = acc[4+tile][q];
        float v = fmaxf(bnA_s[s]*y + bnB_s[s], 0.f);
        v += __shfl_xor(v, 1);
        v += __shfl_xor(v, 2);
        v += __shfl_xor(v, 4);
        v += __shfl_xor(v, 8);
        if ((lane & 15) == 0) red[pg][96 + s] = v;
      }
    }
  }
  __syncthreads();
  if (t < 144) {
    float s = red[0][t] + red[1][t];
    part[((size_t)(b*144) + t)*512 + (blk & 511)] = s;
  }

  // ---- fused routing: last 8 blocks each route one batch ----
  __threadfence();
  __shared__ int sidx;
  if (t == 0) sidx = atomicAdd(cnt, 1);
  __syncthreads();
  int idx = sidx;
  if (idx < PW1_GRID - 8) return;
  __threadfence();
  int b2 = idx - (PW1_GRID - 8);

  __shared__ float fused[144], hmid[36], rpre[576];
  if (t < 144) {
    const float* pp = part + ((size_t)(b2*144) + t)*512;
    float s = 0.f;
    for (int i = 0; i < 512; i += 4) {
      float4 v = *(const float4*)(pp + i);
      s += (v.x + v.y) + (v.z + v.w);
    }
    fused[t] = s * (1.f/16384.f);
  }
  __syncthreads();
  if (t < 36) {
    float a = 0.f;
    for (int i=0;i<144;i++) a = fmaf(fused[i], fc1[t*144+i], a);
    float rr = fmaxf(a, 0.f);
    hmid[t] = mlp_scale[0]*rr*rr + mlp_bias[0];
  }
  __syncthreads();
  for (int o = t; o < 576; o += 256) {
    float a = 0.f;
    for (int j=0;j<36;j++) a = fmaf(hmid[j], fc2[o*36+j], a);
    rpre[o] = a;
  }
  __syncthreads();
  if (t < 192) {
    float v0 = rpre[t], v1 = rpre[192+t], v2 = rpre[384+t];
    float mx = fmaxf(v0, fmaxf(v1, v2));
    float e0 = expf(v0-mx), e1 = expf(v1-mx), e2 = expf(v2-mx);
    float inv = 1.f/(e0+e1+e2);
    r_out[(b2*3+0)*192+t] = e0*inv;
    r_out[(b2*3+1)*192+t] = e1*inv;
    r_out[(b2*3+2)*192+t] = e2*inv;
  }
}

// =====================================================================
// K_pw2 v1 (MFMA, direct) — unchanged from round 10 (best measured).
// =====================================================================
__global__ __launch_bounds__(256) void k_pw2(
    const float* __restrict__ P, const unsigned short* __restrict__ W2B,
    float* __restrict__ out)
{
  int t = threadIdx.x;
  int lane = t & 63, wv = t >> 6;
  int px0 = blockIdx.x*64 + wv*16;
  int b = px0 >> 14;
  int pxl = px0 & 16383;

  float4_t acc[6];
  #pragma unroll
  for (int nt=0; nt<6; ++nt) acc[nt] = (float4_t){0.f,0.f,0.f,0.f};

  #pragma unroll
  for (int kc=0; kc<6; ++kc) {
    const float* ap = P + (size_t)(b*192 + kc*32 + (lane>>4)*8)*PSTR + pxl + (lane&15);
    short8_t Ah, Al;
    #pragma unroll
    for (int j=0;j<8;j++){
      float v = ap[(size_t)j*PSTR];
      unsigned short h = bf16_rne(v);
      Ah[j] = (short)h;
      Al[j] = (short)bf16_rne(v - bf16_to_f(h));
    }
    const short8_t* b_hi = (const short8_t*)(W2B + (size_t)(0*6+kc)*6*512) + lane;
    const short8_t* b_lo = (const short8_t*)(W2B + (size_t)(1*6+kc)*6*512) + lane;
    #pragma unroll
    for (int nt=0; nt<6; ++nt) {
      short8_t Bh = b_hi[nt*64];
      short8_t Bl = b_lo[nt*64];
      acc[nt] = __builtin_amdgcn_mfma_f32_16x16x32_bf16(Ah, Bh, acc[nt], 0,0,0);
      acc[nt] = __builtin_amdgcn_mfma_f32_16x16x32_bf16(Ah, Bl, acc[nt], 0,0,0);
      acc[nt] = __builtin_amdgcn_mfma_f32_16x16x32_bf16(Al, Bh, acc[nt], 0,0,0);
    }
  }
  #pragma unroll
  for (int nt=0; nt<6; ++nt) {
    #pragma unroll
    for (int q=0;q<4;q++){
      int px = px0 + (lane>>4)*4 + q;
      out[(size_t)px*96 + nt*16 + (lane&15)] = acc[nt][q];
    }
  }
}

// =====================================================================
// K_spectral v5: single 1536-block dispatch (round-10 verified).
// =====================================================================
__device__ __forceinline__ float2 c_add(float2 a, float2 b){ return make_float2(a.x+b.x, a.y+b.y); }
__device__ __forceinline__ float2 c_sub(float2 a, float2 b){ return make_float2(a.x-b.x, a.y-b.y); }
__device__ __forceinline__ float2 c_mul(float2 a, float2 w){ return make_float2(a.x*w.x - a.y*w.y, a.x*w.y + a.y*w.x); }
__device__ __forceinline__ float2 c_mulc(float2 a, float2 w){ return make_float2(a.x*w.x + a.y*w.y, a.y*w.x - a.x*w.y); }

__device__ __forceinline__ void dif4(float2* S, const float2* TW,
    int a0, int a1, int a2, int a3, int t1, int t2, int t3)
{
  float2 x0=S[a0], x1=S[a1], x2=S[a2], x3=S[a3];
  float2 u = c_add(x0,x2), d0 = c_sub(x0,x2);
  float2 s = c_add(x1,x3), d1 = c_sub(x1,x3);
  float2 w = c_mul(d0, TW[t1]);
  float2 v = c_mul(d1, TW[t2]);
  float2 t3w = TW[t3];
  S[a0] = c_add(u,s);
  S[a1] = c_mul(c_sub(u,s), t3w);
  S[a2] = c_add(w,v);
  S[a3] = c_mul(c_sub(w,v), t3w);
}

__device__ __forceinline__ void dit4(float2* S, const float2* TW,
    int a0, int a1, int a2, int a3, int tA, int tB, int tC)
{
  float2 x0=S[a0], x1=S[a1], x2=S[a2], x3=S[a3];
  float2 wA = TW[tA];
  float2 x1t = c_mulc(x1, wA), x3t = c_mulc(x3, wA);
  float2 u = c_add(x0,x1t), v = c_sub(x0,x1t);
  float2 s = c_add(x2,x3t), w = c_sub(x2,x3t);
  float2 st = c_mulc(s, TW[tB]);
  float2 wt = c_mulc(w, TW[tC]);
  S[a0] = c_add(u, st);
  S[a2] = c_sub(u, st);
  S[a1] = c_add(v, wt);
  S[a3] = c_sub(v, wt);
}

__global__ __launch_bounds__(512, 4) void k_spectral(
    float* __restrict__ P, const float* __restrict__ filt, const float* __restrict__ r)
{
  __shared__ float2 S[128*LSTR];   // 68,608 B
  __shared__ float2 TW[64];
  int t = threadIdx.x;
  int lane = t & 63, wid = t >> 6;

  int i = blockIdx.x;
  int b = (i >> 3) & 7;
  int m = (i & 7) * 24 + (i >> 6);
  float* plane = P + ((size_t)b*192 + m) * PSTR;

  {
    float ang = -6.283185307179586477f * (float)lane / 128.f;
    TW[lane] = make_float2(cosf(ang), sinf(ang));
  }

  // ---- load + even/odd pack (wave-owned rows 16w..16w+15) ----
  for (int it = 0; it < 8; ++it) {
    int row = 16*wid + (lane>>5) + 2*it;
    int j   = lane & 31;
    float4 v = ((const float4*)plane)[row*32 + j];
    int base = row*LSTR + 2*j;
    S[base]   = make_float2(v.x, v.y);
    S[base+1] = make_float2(v.z, v.w);
  }
  float r0 = r[(b*3+0)*192+m];
  float r1 = r[(b*3+1)*192+m];
  float r2 = r[(b*3+2)*192+m];

  // ---- forward rows: 3 radix-4 passes, wave-owned, NO barriers ----
  #pragma unroll
  for (int ps = 0; ps < 3; ++ps) {
    const int lh = 5 - 2*ps;               // 5,3,1
    const int h1 = 1 << lh, h2 = h1 >> 1;
    #pragma unroll
    for (int it = 0; it < 4; ++it) {
      int g = lane & 15;
      int row = 16*wid + (lane>>4) + 4*it;
      int k = g & (h2-1), blk = g >> (lh-1);
      int base = row*LSTR + blk*(2*h1) + k;
      dif4(S,TW, base, base+h2, base+h1, base+h1+h2,
           k << (6-lh), (k+h2) << (6-lh), k << (7-lh));
    }
  }

  // ---- unpack 65-bin half spectrum (row-fast lanes, NO barrier) ----
  for (int it = 0; it < 9; ++it) {
    int k   = (lane>>4) + 4*it;
    int row = 16*wid + (lane & 15);
    if (k <= 32) {
      int base = row*LSTR;
      if (k == 0) {
        float2 z = S[base];
        S[base]    = make_float2(z.x + z.y, 0.f);
        S[base+64] = make_float2(z.x - z.y, 0.f);
      } else {
        int a = __brev((unsigned)k) >> 26;
        int bidx = __brev((unsigned)(64-k)) >> 26;
        float2 A = S[base+a], B = S[base+bidx];
        float sr_ = 0.5f*(A.x+B.x), si_ = 0.5f*(A.y-B.y);
        float dr  = 0.5f*(A.x-B.x), di  = 0.5f*(A.y+B.y);
        float2 wq = TW[k];
        float tr = wq.x*di + wq.y*dr;
        float ti = -(wq.x*dr - wq.y*di);
        S[base+a]    = make_float2(sr_ + tr,  si_ + ti);
        S[base+bidx] = make_float2(sr_ - tr, -si_ + ti);
      }
    }
  }
  __syncthreads();                         // bar1: rows -> cols

  // ---- forward cols: 3 radix-4 passes (col-fast, block-wide) ----
  #pragma unroll
  for (int ps = 0; ps < 3; ++ps) {
    const int lh = 6 - 2*ps;               // 6,4,2
    const int h1 = 1 << lh, h2 = h1 >> 1;
    for (int it = 0; it < 5; ++it) {
      int idx = t + 512*it;
      if (idx < 65*32) {
        int g = idx / 65, col = idx - g*65;
        int k = g & (h2-1), blk = g >> (lh-1);
        int p = blk*(2*h1) + k;
        dif4(S,TW, p*LSTR+col, (p+h2)*LSTR+col, (p+h1)*LSTR+col, (p+h1+h2)*LSTR+col,
             k << (6-lh), (k+h2) << (6-lh), k << (7-lh));
      }
    }
    __syncthreads();                       // bar2,3,4
  }

  // ---- fused: final radix-2 (span 1) + routed spectral multiply ----
  {
    const float2* fb0 = (const float2*)filt + (size_t)(0*192+m)*8320;
    const float2* fb1 = (const float2*)filt + (size_t)(1*192+m)*8320;
    const float2* fb2 = (const float2*)filt + (size_t)(2*192+m)*8320;
    const float inv = 1.f/8192.f;
    for (int it = 0; it < 9; ++it) {
      int idx = t + 512*it;
      if (idx < 65*64) {
        int f = idx / 65, fw = idx - f*65;
        int j = __brev((unsigned)f) >> 26;
        int cc = (fw == 64) ? 64 : (__brev((unsigned)fw) >> 26);
        int a0 = (2*j)*LSTR + cc, a1 = a0 + LSTR;
        float2 u = S[a0], v = S[a1];
        float2 e = c_add(u,v), o = c_sub(u,v);
        float2 f00=fb0[idx],      f10=fb1[idx],      f20=fb2[idx];
        float2 f01=fb0[idx+4160], f11=fb1[idx+4160], f21=fb2[idx+4160];
        float cr0 = (r0*f00.x + r1*f10.x + r2*f20.x) * inv;
        float ci0 = (r0*f00.y + r1*f10.y + r2*f20.y) * inv;
        float cr1 = (r0*f01.x + r1*f11.x + r2*f21.x) * inv;
        float ci1 = (r0*f01.y + r1*f11.y + r2*f21.y) * inv;
        S[a0] = make_float2(e.x*cr0 - e.y*ci0, e.x*ci0 + e.y*cr0);
        S[a1] = make_float2(o.x*cr1 - o.y*ci1, o.x*ci1 + o.y*cr1);
      }
    }
  }
  __syncthreads();                         // bar5

  // ---- inverse cols: 3 DIT passes (col-fast, block-wide) ----
  #pragma unroll
  for (int ps = 0; ps < 3; ++ps) {
    const int la = 2*ps;                   // 0,2,4
    const int h = 1 << la;
    for (int it = 0; it < 5; ++it) {
      int idx = t + 512*it;
      if (idx < 65*32) {
        int g = idx / 65, col = idx - g*65;
        int k = g & (h-1), blk = g >> la;
        int p = blk*(4*h) + k;
        dit4(S,TW, p*LSTR+col, (p+h)*LSTR+col, (p+2*h)*LSTR+col, (p+3*h)*LSTR+col,
             k << (6-la), k << (5-la), (k+h) << (5-la));
      }
    }
    __syncthreads();                       // bar6,7,8
  }
  // final radix-2 span 64, conj twiddle (col-fast, block-wide)
  for (int it = 0; it < 9; ++it) {
    int idx = t + 512*it;
    if (idx < 65*64) {
      int k = idx / 65, col = idx - k*65;
      int a0 = k*LSTR + col, a1 = a0 + 64*LSTR;
      float2 u = S[a0], xv = S[a1];
      float2 xt = c_mulc(xv, TW[k]);
      S[a0] = c_add(u,xt); S[a1] = c_sub(u,xt);
    }
  }
  __syncthreads();                         // bar9: cols -> rows

  // ---- pack: drop imag at fw=0,64 (row-fast lanes, NO barrier) ----
  for (int it = 0; it < 9; ++it) {
    int k   = (lane>>4) + 4*it;
    int row = 16*wid + (lane & 15);
    if (k <= 32) {
      int base = row*LSTR;
      if (k == 0) {
        float ar = S[base].x;
        float cr = S[base+64].x;
        S[base] = make_float2(0.5f*(ar+cr), 0.5f*(ar-cr));
      } else {
        int a = __brev((unsigned)k) >> 26;
        int bidx = __brev((unsigned)(64-k)) >> 26;
        float2 A = S[base+a], B = S[base+bidx];
        float sr_ = 0.5f*(A.x+B.x), si_ = 0.5f*(A.y-B.y);
        float dr  = 0.5f*(A.x-B.x), di  = 0.5f*(A.y+B.y);
        float2 wq = TW[k];
        float tr2 = wq.y*dr - wq.x*di;
        float ti2 = wq.x*dr + wq.y*di;
        S[base+a]    = make_float2(sr_ + tr2,  si_ + ti2);
        S[base+bidx] = make_float2(sr_ - tr2, -si_ + ti2);
      }
    }
  }

  // ---- inverse rows: 3 DIT passes, wave-owned, NO barriers ----
  #pragma unroll
  for (int ps = 0; ps < 3; ++ps) {
    const int la = 2*ps;                   // 0,2,4
    const int h = 1 << la;
    #pragma unroll
    for (int it = 0; it < 4; ++it) {
      int g = lane & 15;
      int row = 16*wid + (lane>>4) + 4*it;
      int k = g & (h-1), blk = g >> la;
      int base = row*LSTR + blk*(4*h) + k;
      dit4(S,TW, base, base+h, base+2*h, base+3*h,
           k << (6-la), k << (5-la), (k+h) << (5-la));
    }
  }

  // ---- store (wave-owned rows, NO barrier) ----
  for (int it = 0; it < 8; ++it) {
    int row = 16*wid + (lane>>5) + 2*it;
    int j   = lane & 31;
    int base = row*LSTR + 2*j;
    float2 z0 = S[base], z1 = S[base+1];
    float4 v; v.x = z0.x; v.y = z0.y; v.z = z1.x; v.w = z1.y;
    ((float4*)plane)[row*32 + j] = v;
  }
}

// =====================================================================
extern "C" void kernel_launch(void* const* d_in, const int* in_sizes, int n_in,
                              void* d_out, int out_size, void* d_ws, size_t ws_size,
                              hipStream_t stream) {
  const float* x          = (const float*)d_in[0];
  const float* w1         = (const float*)d_in[1];
  const float* soa1_scale = (const float*)d_in[2];
  const float* soa1_bias  = (const float*)d_in[3];
  const float* cw0        = (const float*)d_in[4];
  const float* cw1        = (const float*)d_in[5];
  const float* cw2        = (const float*)d_in[6];
  const float* sp_w       = (const float*)d_in[7];
  const float* bn_gamma   = (const float*)d_in[8];
  const float* bn_beta    = (const float*)d_in[9];
  const float* bn_mean    = (const float*)d_in[10];
  const float* bn_var     = (const float*)d_in[11];
  const float* fc1        = (const float*)d_in[12];
  const float* mlp_scale  = (const float*)d_in[13];
  const float* mlp_bias   = (const float*)d_in[14];
  const float* fc2        = (const float*)d_in[15];
  const float* w2         = (const float*)d_in[16];
  float* out = (float*)d_out;

  float* ws   = (float*)d_ws;
  float* P    = ws + P_OFF;
  float* filt = ws + FILT_OFF;
  float* part = ws + PART_OFF;
  float* rbuf = ws + R_OFF;
  unsigned short* W1B = (unsigned short*)(ws + W1B_OFF);
  unsigned short* W2B = (unsigned short*)(ws + W2B_OFF);
  int* cnt = (int*)(ws + CNT_OFF);

  k_prep_filt<<<612, 256, 0, stream>>>(w1, sp_w, w2, cw0, cw1, cw2, W1B, W2B, filt, cnt);
  k_pw1      <<<PW1_GRID, 256, 0, stream>>>(x, W1B, soa1_scale, soa1_bias,
                                            bn_gamma, bn_beta, bn_mean, bn_var,
                                            P, part, cnt,
                                            fc1, fc2, mlp_scale, mlp_bias, rbuf);
  k_spectral <<<1536,512, 0, stream>>>(P, filt, rbuf);
  k_pw2      <<<2048,256, 0, stream>>>(P, W2B, out);
}

// Round 12
// 358.886 us; speedup vs baseline: 2.6190x; 2.6190x over previous
//
#include <hip/hip_runtime.h>
#include <math.h>

// ---------------- problem constants ----------------
#define BB    8
#define HH    128
#define WW    128
#define DIM   96
#define MED   192
#define HWPX  16384        // H*W
#define PSTR  16672        // padded P plane stride (floats): 66688 B = 128*521
#define FWH   65
#define LSTR  67           // spectral LDS row stride in float2 units

// workspace layout (float offsets)
#define P_OFF     0
#define P_SZ      (8*192*PSTR)             // x_pre / xsp planes [b][m][PSTR]
#define FILT_OFF  (P_OFF + P_SZ)
#define FILT_SZ   (3*192*128*65*2)         // filt [s][m][fh][fw] complex (NATURAL layout)
#define PART_OFF  (FILT_OFF + FILT_SZ)     // pw1 routing partials [b][144][256]
#define PART_SZ   (8*144*256)
#define R_OFF     (PART_OFF + PART_SZ)     // r  8*3*192
#define W1B_OFF   (R_OFF + 4608)           // 2*3*15*512 = 46080 ushort = 23040 float slots
#define W2B_OFF   (W1B_OFF + 23040)        // 36864 ushort

typedef __attribute__((ext_vector_type(8))) short short8_t;
typedef __attribute__((ext_vector_type(4))) float float4_t;

__device__ __forceinline__ unsigned short bf16_rne(float f){
  unsigned u = __float_as_uint(f);
  unsigned r = (u + 0x7FFFu + ((u>>16)&1u)) >> 16;
  return (unsigned short)r;
}
__device__ __forceinline__ float bf16_to_f(unsigned short h){
  return __uint_as_float(((unsigned)h) << 16);
}

// =====================================================================
// K_prep_filt: FUSED independent preprocessing (saves one launch).
//  blocks 0..35   : pack [w1 ; sp_w] and w2 into MFMA fragment order
//  blocks 36..611 : separable bicubic filter resize (one block per (s,m))
// NOTE (r11 lesson): do NOT fuse dependent stages via completion
// counters + __threadfence — device-scope fences in every block's path
// serialize on the 8-XCD non-coherent L2s (pw1 went 72 -> 660us).
// =====================================================================
__device__ __forceinline__ float cubicw(float tt){
  float t = fabsf(tt), t2=t*t, t3=t2*t;
  if (t <= 1.f) return 1.25f*t3 - 2.25f*t2 + 1.f;
  if (t < 2.f)  return -0.75f*t3 + 3.75f*t2 - 6.f*t + 3.f;
  return 0.f;
}

__global__ __launch_bounds__(256) void k_prep_filt(
    const float* __restrict__ w1, const float* __restrict__ sp_w,
    const float* __restrict__ w2,
    const float* __restrict__ cw0, const float* __restrict__ cw1,
    const float* __restrict__ cw2,
    unsigned short* __restrict__ W1B, unsigned short* __restrict__ W2B,
    float* __restrict__ filt)
{
  __shared__ float2 T[128][13];
  int bx = blockIdx.x;
  int t = threadIdx.x;

  if (bx < 36) {
    // ---- weight packing ----
    int tid = t + bx*256;
    int nthr = 256*36;
    for (int i = tid; i < 2*3*15*512; i += nthr) {
      int j = i & 7, l = (i>>3) & 63;
      int nt = (i>>9) % 15, kc = ((i>>9)/15) % 3, term = i / (3*15*512);
      int r = nt*16 + (l&15);
      int c = kc*32 + (l>>4)*8 + j;
      float v = (r < 192) ? w1[r*96 + c] : sp_w[(r-192)*96 + c];
      unsigned short hi = bf16_rne(v);
      W1B[i] = (term==0) ? hi : bf16_rne(v - bf16_to_f(hi));
    }
    for (int i = tid; i < 2*6*6*512; i += nthr) {
      int j = i & 7, l = (i>>3) & 63;
      int nt = (i>>9) % 6, kc = ((i>>9)/6) % 6, term = i / (6*6*512);
      int cp = nt*16 + (l&15);
      int m  = kc*32 + (l>>4)*8 + j;
      float v = w2[cp*192 + m];
      unsigned short hi = bf16_rne(v);
      W2B[i] = (term==0) ? hi : bf16_rne(v - bf16_to_f(hi));
    }
    return;
  }

  // ---- separable bicubic resize ----
  int fb = bx - 36;
  int s = fb / 192, m = fb - s*192;
  const float* cw = (s==0) ? cw0 : ((s==1) ? cw1 : cw2);
  const int SH = (s==0) ? 16 : ((s==1) ? 8 : 24);
  const int SW = (s==0) ? 9  : ((s==1) ? 4 : 13);

  // phase 1: h-resize into T[128][SW]
  for (int i = t; i < 128*SW; i += 256) {
    int fh = i / SW, iw = i - fh*SW;
    float sh = fh * (float)(SH-1) / 127.f;
    int fh0 = (int)floorf(sh);
    float2 acc = make_float2(0.f, 0.f);
    #pragma unroll
    for (int ka=0; ka<4; ++ka) {
      int kk = fh0-1+ka;
      float w = cubicw(sh - (float)kk);
      int ih = min(max(kk,0), SH-1);
      float2 v = *(const float2*)(cw + (size_t)((ih*SW + iw)*192 + m)*2);
      acc.x = fmaf(w, v.x, acc.x);
      acc.y = fmaf(w, v.y, acc.y);
    }
    T[fh][iw] = acc;
  }
  __syncthreads();

  // phase 2: w-resize from LDS broadcast
  float2* outp = (float2*)filt + (size_t)(s*192+m)*8320;
  for (int i = t; i < 128*65; i += 256) {
    int fh = i / 65, fw = i - fh*65;
    float sw = fw * (float)(SW-1) / 64.f;
    int fw0 = (int)floorf(sw);
    float2 acc = make_float2(0.f, 0.f);
    #pragma unroll
    for (int kb=0; kb<4; ++kb) {
      int jj = fw0-1+kb;
      float w = cubicw(sw - (float)jj);
      int iw = min(max(jj,0), SW-1);
      float2 v = T[fh][iw];
      acc.x = fmaf(w, v.x, acc.x);
      acc.y = fmaf(w, v.y, acc.y);
    }
    outp[i] = acc;
  }
}

// =====================================================================
// K_pw1 v2 (MFMA, fused routing stats): direct scattered P stores +
// non-atomic partials.  Best measured structure (r7: 72.5us).
// =====================================================================
__global__ __launch_bounds__(256) void k_pw1(
    const float* __restrict__ x, const unsigned short* __restrict__ W1B,
    const float* __restrict__ soa_scale, const float* __restrict__ soa_bias,
    const float* __restrict__ bn_gamma, const float* __restrict__ bn_beta,
    const float* __restrict__ bn_mean, const float* __restrict__ bn_var,
    float* __restrict__ P, float* __restrict__ part)
{
  __shared__ float red[4][144];
  __shared__ float bnA_s[48], bnB_s[48];
  int t = threadIdx.x;
  int lane = t & 63, wv = t >> 6;
  if (t < 48) {
    float a = bn_gamma[t] * rsqrtf(bn_var[t] + 1e-5f);
    bnA_s[t] = a; bnB_s[t] = bn_beta[t] - bn_mean[t]*a;
  }
  int blk = blockIdx.x;
  int px0 = blk*64 + wv*16;
  int b = (blk*64) >> 14;
  int pxl = px0 & 16383;
  int g = lane >> 4;

  float4_t acc[15];
  #pragma unroll
  for (int nt=0; nt<15; ++nt) acc[nt] = (float4_t){0.f,0.f,0.f,0.f};

  #pragma unroll
  for (int kc=0; kc<3; ++kc) {
    const float* xp = x + (size_t)(px0 + (lane&15))*96 + kc*32 + g*8;
    float4 v0 = *(const float4*)xp;
    float4 v1 = *(const float4*)(xp+4);
    float vv[8] = {v0.x,v0.y,v0.z,v0.w, v1.x,v1.y,v1.z,v1.w};
    #pragma unroll
    for (int j=0;j<8;j++){
      float s = vv[j];
      s += __shfl_xor(s, 1);
      s += __shfl_xor(s, 2);
      s += __shfl_xor(s, 4);
      s += __shfl_xor(s, 8);
      if ((lane & 15) == 0) red[wv][kc*32 + g*8 + j] = s;
    }
    short8_t Bh, Bl;
    #pragma unroll
    for (int j=0;j<8;j++){
      unsigned short h = bf16_rne(vv[j]);
      Bh[j] = (short)h;
      Bl[j] = (short)bf16_rne(vv[j] - bf16_to_f(h));
    }
    const short8_t* a_hi = (const short8_t*)(W1B + (size_t)(0*3+kc)*15*512) + lane;
    const short8_t* a_lo = (const short8_t*)(W1B + (size_t)(1*3+kc)*15*512) + lane;
    #pragma unroll
    for (int nt=0; nt<15; ++nt) {
      short8_t Ah = a_hi[nt*64];
      short8_t Al = a_lo[nt*64];
      acc[nt] = __builtin_amdgcn_mfma_f32_16x16x32_bf16(Ah, Bh, acc[nt], 0,0,0);
      acc[nt] = __builtin_amdgcn_mfma_f32_16x16x32_bf16(Ah, Bl, acc[nt], 0,0,0);
      acc[nt] = __builtin_amdgcn_mfma_f32_16x16x32_bf16(Al, Bh, acc[nt], 0,0,0);
    }
  }
  float sc = soa_scale[0], bi = soa_bias[0];
  #pragma unroll
  for (int nt=0; nt<12; ++nt) {
    #pragma unroll
    for (int q=0;q<4;q++){
      float d = acc[nt][q];
      float v = fmaxf(d, 0.f);
      d = sc*v*v + bi;
      int mp = nt*16 + g*4 + q;
      P[(size_t)(b*192 + mp)*PSTR + pxl + (lane&15)] = d;
    }
  }
  #pragma unroll
  for (int tile=0; tile<3; ++tile) {
    #pragma unroll
    for (int q=0;q<4;q++){
      int s = tile*16 + g*4 + q;
      float y = acc[12+tile][q];
      float v = fmaxf(bnA_s[s]*y + bnB_s[s], 0.f);
      v += __shfl_xor(v, 1);
      v += __shfl_xor(v, 2);
      v += __shfl_xor(v, 4);
      v += __shfl_xor(v, 8);
      if ((lane & 15) == 0) red[wv][96 + s] = v;
    }
  }
  __syncthreads();
  if (t < 144) {
    float s = red[0][t] + red[1][t] + red[2][t] + red[3][t];
    part[((size_t)(b*144) + t)*256 + (blk & 255)] = s;
  }
}

// =====================================================================
// K_pw2 v1 (MFMA, direct): the r4-best structure — strided scalar P
// reads, scattered out stores.  Every LDS-staging variant measured
// equal-or-worse.
// =====================================================================
__global__ __launch_bounds__(256) void k_pw2(
    const float* __restrict__ P, const unsigned short* __restrict__ W2B,
    float* __restrict__ out)
{
  int t = threadIdx.x;
  int lane = t & 63, wv = t >> 6;
  int px0 = blockIdx.x*64 + wv*16;
  int b = px0 >> 14;
  int pxl = px0 & 16383;

  float4_t acc[6];
  #pragma unroll
  for (int nt=0; nt<6; ++nt) acc[nt] = (float4_t){0.f,0.f,0.f,0.f};

  #pragma unroll
  for (int kc=0; kc<6; ++kc) {
    const float* ap = P + (size_t)(b*192 + kc*32 + (lane>>4)*8)*PSTR + pxl + (lane&15);
    short8_t Ah, Al;
    #pragma unroll
    for (int j=0;j<8;j++){
      float v = ap[(size_t)j*PSTR];
      unsigned short h = bf16_rne(v);
      Ah[j] = (short)h;
      Al[j] = (short)bf16_rne(v - bf16_to_f(h));
    }
    const short8_t* b_hi = (const short8_t*)(W2B + (size_t)(0*6+kc)*6*512) + lane;
    const short8_t* b_lo = (const short8_t*)(W2B + (size_t)(1*6+kc)*6*512) + lane;
    #pragma unroll
    for (int nt=0; nt<6; ++nt) {
      short8_t Bh = b_hi[nt*64];
      short8_t Bl = b_lo[nt*64];
      acc[nt] = __builtin_amdgcn_mfma_f32_16x16x32_bf16(Ah, Bh, acc[nt], 0,0,0);
      acc[nt] = __builtin_amdgcn_mfma_f32_16x16x32_bf16(Ah, Bl, acc[nt], 0,0,0);
      acc[nt] = __builtin_amdgcn_mfma_f32_16x16x32_bf16(Al, Bh, acc[nt], 0,0,0);
    }
  }
  #pragma unroll
  for (int nt=0; nt<6; ++nt) {
    #pragma unroll
    for (int q=0;q<4;q++){
      int px = px0 + (lane>>4)*4 + q;
      out[(size_t)px*96 + nt*16 + (lane&15)] = acc[nt][q];
    }
  }
}

// =====================================================================
// K_route2: reduce pw1 partials, then per-batch MLP + softmax.
// =====================================================================
__global__ __launch_bounds__(256) void k_route2(
    const float* __restrict__ part,
    const float* __restrict__ fc1, const float* __restrict__ fc2,
    const float* __restrict__ mlp_scale, const float* __restrict__ mlp_bias,
    float* __restrict__ r_out)
{
  __shared__ float fused[144], hmid[36], rpre[576];
  int t = threadIdx.x, b = blockIdx.x;
  if (t < 144) {
    const float* pp = part + ((size_t)(b*144) + t)*256;
    float s = 0.f;
    for (int i = 0; i < 256; i += 4) {
      float4 v = *(const float4*)(pp + i);
      s += (v.x + v.y) + (v.z + v.w);
    }
    fused[t] = s * (1.f/16384.f);
  }
  __syncthreads();
  if (t < 36) {
    float a = 0.f;
    for (int i=0;i<144;i++) a = fmaf(fused[i], fc1[t*144+i], a);
    float rr = fmaxf(a, 0.f);
    hmid[t] = mlp_scale[0]*rr*rr + mlp_bias[0];
  }
  __syncthreads();
  for (int o = t; o < 576; o += 256) {
    float a = 0.f;
    for (int j=0;j<36;j++) a = fmaf(hmid[j], fc2[o*36+j], a);
    rpre[o] = a;
  }
  __syncthreads();
  if (t < 192) {
    float v0 = rpre[t], v1 = rpre[192+t], v2 = rpre[384+t];
    float mx = fmaxf(v0, fmaxf(v1, v2));
    float e0 = expf(v0-mx), e1 = expf(v1-mx), e2 = expf(v2-mx);
    float inv = 1.f/(e0+e1+e2);
    r_out[(b*3+0)*192+t] = e0*inv;
    r_out[(b*3+1)*192+t] = e1*inv;
    r_out[(b*3+2)*192+t] = e2*inv;
  }
}

// =====================================================================
// K_spectral v5: single 1536-block dispatch (round-10 verified):
// consecutive-row wave ownership, 9 barriers, fused radix2+multiply,
// XCD-aware grid swizzle.
// =====================================================================
__device__ __forceinline__ float2 c_add(float2 a, float2 b){ return make_float2(a.x+b.x, a.y+b.y); }
__device__ __forceinline__ float2 c_sub(float2 a, float2 b){ return make_float2(a.x-b.x, a.y-b.y); }
__device__ __forceinline__ float2 c_mul(float2 a, float2 w){ return make_float2(a.x*w.x - a.y*w.y, a.x*w.y + a.y*w.x); }
__device__ __forceinline__ float2 c_mulc(float2 a, float2 w){ return make_float2(a.x*w.x + a.y*w.y, a.y*w.x - a.x*w.y); }

__device__ __forceinline__ void dif4(float2* S, const float2* TW,
    int a0, int a1, int a2, int a3, int t1, int t2, int t3)
{
  float2 x0=S[a0], x1=S[a1], x2=S[a2], x3=S[a3];
  float2 u = c_add(x0,x2), d0 = c_sub(x0,x2);
  float2 s = c_add(x1,x3), d1 = c_sub(x1,x3);
  float2 w = c_mul(d0, TW[t1]);
  float2 v = c_mul(d1, TW[t2]);
  float2 t3w = TW[t3];
  S[a0] = c_add(u,s);
  S[a1] = c_mul(c_sub(u,s), t3w);
  S[a2] = c_add(w,v);
  S[a3] = c_mul(c_sub(w,v), t3w);
}

__device__ __forceinline__ void dit4(float2* S, const float2* TW,
    int a0, int a1, int a2, int a3, int tA, int tB, int tC)
{
  float2 x0=S[a0], x1=S[a1], x2=S[a2], x3=S[a3];
  float2 wA = TW[tA];
  float2 x1t = c_mulc(x1, wA), x3t = c_mulc(x3, wA);
  float2 u = c_add(x0,x1t), v = c_sub(x0,x1t);
  float2 s = c_add(x2,x3t), w = c_sub(x2,x3t);
  float2 st = c_mulc(s, TW[tB]);
  float2 wt = c_mulc(w, TW[tC]);
  S[a0] = c_add(u, st);
  S[a2] = c_sub(u, st);
  S[a1] = c_add(v, wt);
  S[a3] = c_sub(v, wt);
}

__global__ __launch_bounds__(512, 4) void k_spectral(
    float* __restrict__ P, const float* __restrict__ filt, const float* __restrict__ r)
{
  __shared__ float2 S[128*LSTR];   // 68,608 B
  __shared__ float2 TW[64];
  int t = threadIdx.x;
  int lane = t & 63, wid = t >> 6;

  int i = blockIdx.x;
  int b = (i >> 3) & 7;
  int m = (i & 7) * 24 + (i >> 6);
  float* plane = P + ((size_t)b*192 + m) * PSTR;

  {
    float ang = -6.283185307179586477f * (float)lane / 128.f;
    TW[lane] = make_float2(cosf(ang), sinf(ang));
  }

  // ---- load + even/odd pack (wave-owned rows 16w..16w+15) ----
  for (int it = 0; it < 8; ++it) {
    int row = 16*wid + (lane>>5) + 2*it;
    int j   = lane & 31;
    float4 v = ((const float4*)plane)[row*32 + j];
    int base = row*LSTR + 2*j;
    S[base]   = make_float2(v.x, v.y);
    S[base+1] = make_float2(v.z, v.w);
  }
  float r0 = r[(b*3+0)*192+m];
  float r1 = r[(b*3+1)*192+m];
  float r2 = r[(b*3+2)*192+m];

  // ---- forward rows: 3 radix-4 passes, wave-owned, NO barriers ----
  #pragma unroll
  for (int ps = 0; ps < 3; ++ps) {
    const int lh = 5 - 2*ps;               // 5,3,1
    const int h1 = 1 << lh, h2 = h1 >> 1;
    #pragma unroll
    for (int it = 0; it < 4; ++it) {
      int g = lane & 15;
      int row = 16*wid + (lane>>4) + 4*it;
      int k = g & (h2-1), blk = g >> (lh-1);
      int base = row*LSTR + blk*(2*h1) + k;
      dif4(S,TW, base, base+h2, base+h1, base+h1+h2,
           k << (6-lh), (k+h2) << (6-lh), k << (7-lh));
    }
  }

  // ---- unpack 65-bin half spectrum (row-fast lanes, NO barrier) ----
  for (int it = 0; it < 9; ++it) {
    int k   = (lane>>4) + 4*it;
    int row = 16*wid + (lane & 15);
    if (k <= 32) {
      int base = row*LSTR;
      if (k == 0) {
        float2 z = S[base];
        S[base]    = make_float2(z.x + z.y, 0.f);
        S[base+64] = make_float2(z.x - z.y, 0.f);
      } else {
        int a = __brev((unsigned)k) >> 26;
        int bidx = __brev((unsigned)(64-k)) >> 26;
        float2 A = S[base+a], B = S[base+bidx];
        float sr_ = 0.5f*(A.x+B.x), si_ = 0.5f*(A.y-B.y);
        float dr  = 0.5f*(A.x-B.x), di  = 0.5f*(A.y+B.y);
        float2 wq = TW[k];
        float tr = wq.x*di + wq.y*dr;
        float ti = -(wq.x*dr - wq.y*di);
        S[base+a]    = make_float2(sr_ + tr,  si_ + ti);
        S[base+bidx] = make_float2(sr_ - tr, -si_ + ti);
      }
    }
  }
  __syncthreads();                         // bar1: rows -> cols

  // ---- forward cols: 3 radix-4 passes (col-fast, block-wide) ----
  #pragma unroll
  for (int ps = 0; ps < 3; ++ps) {
    const int lh = 6 - 2*ps;               // 6,4,2
    const int h1 = 1 << lh, h2 = h1 >> 1;
    for (int it = 0; it < 5; ++it) {
      int idx = t + 512*it;
      if (idx < 65*32) {
        int g = idx / 65, col = idx - g*65;
        int k = g & (h2-1), blk = g >> (lh-1);
        int p = blk*(2*h1) + k;
        dif4(S,TW, p*LSTR+col, (p+h2)*LSTR+col, (p+h1)*LSTR+col, (p+h1+h2)*LSTR+col,
             k << (6-lh), (k+h2) << (6-lh), k << (7-lh));
      }
    }
    __syncthreads();                       // bar2,3,4
  }

  // ---- fused: final radix-2 (span 1) + routed spectral multiply ----
  {
    const float2* fb0 = (const float2*)filt + (size_t)(0*192+m)*8320;
    const float2* fb1 = (const float2*)filt + (size_t)(1*192+m)*8320;
    const float2* fb2 = (const float2*)filt + (size_t)(2*192+m)*8320;
    const float inv = 1.f/8192.f;
    for (int it = 0; it < 9; ++it) {
      int idx = t + 512*it;
      if (idx < 65*64) {
        int f = idx / 65, fw = idx - f*65;
        int j = __brev((unsigned)f) >> 26;
        int cc = (fw == 64) ? 64 : (__brev((unsigned)fw) >> 26);
        int a0 = (2*j)*LSTR + cc, a1 = a0 + LSTR;
        float2 u = S[a0], v = S[a1];
        float2 e = c_add(u,v), o = c_sub(u,v);
        float2 f00=fb0[idx],      f10=fb1[idx],      f20=fb2[idx];
        float2 f01=fb0[idx+4160], f11=fb1[idx+4160], f21=fb2[idx+4160];
        float cr0 = (r0*f00.x + r1*f10.x + r2*f20.x) * inv;
        float ci0 = (r0*f00.y + r1*f10.y + r2*f20.y) * inv;
        float cr1 = (r0*f01.x + r1*f11.x + r2*f21.x) * inv;
        float ci1 = (r0*f01.y + r1*f11.y + r2*f21.y) * inv;
        S[a0] = make_float2(e.x*cr0 - e.y*ci0, e.x*ci0 + e.y*cr0);
        S[a1] = make_float2(o.x*cr1 - o.y*ci1, o.x*ci1 + o.y*cr1);
      }
    }
  }
  __syncthreads();                         // bar5

  // ---- inverse cols: 3 DIT passes (col-fast, block-wide) ----
  #pragma unroll
  for (int ps = 0; ps < 3; ++ps) {
    const int la = 2*ps;                   // 0,2,4
    const int h = 1 << la;
    for (int it = 0; it < 5; ++it) {
      int idx = t + 512*it;
      if (idx < 65*32) {
        int g = idx / 65, col = idx - g*65;
        int k = g & (h-1), blk = g >> la;
        int p = blk*(4*h) + k;
        dit4(S,TW, p*LSTR+col, (p+h)*LSTR+col, (p+2*h)*LSTR+col, (p+3*h)*LSTR+col,
             k << (6-la), k << (5-la), (k+h) << (5-la));
      }
    }
    __syncthreads();                       // bar6,7,8
  }
  // final radix-2 span 64, conj twiddle (col-fast, block-wide)
  for (int it = 0; it < 9; ++it) {
    int idx = t + 512*it;
    if (idx < 65*64) {
      int k = idx / 65, col = idx - k*65;
      int a0 = k*LSTR + col, a1 = a0 + 64*LSTR;
      float2 u = S[a0], xv = S[a1];
      float2 xt = c_mulc(xv, TW[k]);
      S[a0] = c_add(u,xt); S[a1] = c_sub(u,xt);
    }
  }
  __syncthreads();                         // bar9: cols -> rows

  // ---- pack: drop imag at fw=0,64 (row-fast lanes, NO barrier) ----
  for (int it = 0; it < 9; ++it) {
    int k   = (lane>>4) + 4*it;
    int row = 16*wid + (lane & 15);
    if (k <= 32) {
      int base = row*LSTR;
      if (k == 0) {
        float ar = S[base].x;
        float cr = S[base+64].x;
        S[base] = make_float2(0.5f*(ar+cr), 0.5f*(ar-cr));
      } else {
        int a = __brev((unsigned)k) >> 26;
        int bidx = __brev((unsigned)(64-k)) >> 26;
        float2 A = S[base+a], B = S[base+bidx];
        float sr_ = 0.5f*(A.x+B.x), si_ = 0.5f*(A.y-B.y);
        float dr  = 0.5f*(A.x-B.x), di  = 0.5f*(A.y+B.y);
        float2 wq = TW[k];
        float tr2 = wq.y*dr - wq.x*di;
        float ti2 = wq.x*dr + wq.y*di;
        S[base+a]    = make_float2(sr_ + tr2,  si_ + ti2);
        S[base+bidx] = make_float2(sr_ - tr2, -si_ + ti2);
      }
    }
  }

  // ---- inverse rows: 3 DIT passes, wave-owned, NO barriers ----
  #pragma unroll
  for (int ps = 0; ps < 3; ++ps) {
    const int la = 2*ps;                   // 0,2,4
    const int h = 1 << la;
    #pragma unroll
    for (int it = 0; it < 4; ++it) {
      int g = lane & 15;
      int row = 16*wid + (lane>>4) + 4*it;
      int k = g & (h-1), blk = g >> la;
      int base = row*LSTR + blk*(4*h) + k;
      dit4(S,TW, base, base+h, base+2*h, base+3*h,
           k << (6-la), k << (5-la), (k+h) << (5-la));
    }
  }

  // ---- store (wave-owned rows, NO barrier) ----
  for (int it = 0; it < 8; ++it) {
    int row = 16*wid + (lane>>5) + 2*it;
    int j   = lane & 31;
    int base = row*LSTR + 2*j;
    float2 z0 = S[base], z1 = S[base+1];
    float4 v; v.x = z0.x; v.y = z0.y; v.z = z1.x; v.w = z1.y;
    ((float4*)plane)[row*32 + j] = v;
  }
}

// =====================================================================
extern "C" void kernel_launch(void* const* d_in, const int* in_sizes, int n_in,
                              void* d_out, int out_size, void* d_ws, size_t ws_size,
                              hipStream_t stream) {
  const float* x          = (const float*)d_in[0];
  const float* w1         = (const float*)d_in[1];
  const float* soa1_scale = (const float*)d_in[2];
  const float* soa1_bias  = (const float*)d_in[3];
  const float* cw0        = (const float*)d_in[4];
  const float* cw1        = (const float*)d_in[5];
  const float* cw2        = (const float*)d_in[6];
  const float* sp_w       = (const float*)d_in[7];
  const float* bn_gamma   = (const float*)d_in[8];
  const float* bn_beta    = (const float*)d_in[9];
  const float* bn_mean    = (const float*)d_in[10];
  const float* bn_var     = (const float*)d_in[11];
  const float* fc1        = (const float*)d_in[12];
  const float* mlp_scale  = (const float*)d_in[13];
  const float* mlp_bias   = (const float*)d_in[14];
  const float* fc2        = (const float*)d_in[15];
  const float* w2         = (const float*)d_in[16];
  float* out = (float*)d_out;

  float* ws   = (float*)d_ws;
  float* P    = ws + P_OFF;
  float* filt = ws + FILT_OFF;
  float* part = ws + PART_OFF;
  float* rbuf = ws + R_OFF;
  unsigned short* W1B = (unsigned short*)(ws + W1B_OFF);
  unsigned short* W2B = (unsigned short*)(ws + W2B_OFF);

  k_prep_filt<<<612, 256, 0, stream>>>(w1, sp_w, w2, cw0, cw1, cw2, W1B, W2B, filt);
  k_pw1      <<<2048,256, 0, stream>>>(x, W1B, soa1_scale, soa1_bias,
                                       bn_gamma, bn_beta, bn_mean, bn_var,
                                       P, part);
  k_route2   <<<8,   256, 0, stream>>>(part, fc1, fc2, mlp_scale, mlp_bias, rbuf);
  k_spectral <<<1536,512, 0, stream>>>(P, filt, rbuf);
  k_pw2      <<<2048,256, 0, stream>>>(P, W2B, out);
}

// Round 15
// 357.743 us; speedup vs baseline: 2.6273x; 1.0032x over previous
//
#include <hip/hip_runtime.h>
#include <math.h>

// ---------------- problem constants ----------------
#define BB    8
#define HH    128
#define WW    128
#define DIM   96
#define MED   192
#define HWPX  16384        // H*W
#define PSTR  16672        // padded P plane stride (floats): 66688 B = 128*521
#define FWH   65
#define LSTR  67           // spectral LDS row stride in float2 units

// workspace layout (float offsets)
#define P_OFF     0
#define P_SZ      (8*192*PSTR)             // x_pre / xsp planes [b][m][PSTR]
#define FILT_OFF  (P_OFF + P_SZ)
#define FILT_SZ   (3*192*65*64*4)          // filtP [s][m][cc][j] float4 (col-owned layout)
#define PART_OFF  (FILT_OFF + FILT_SZ)     // pw1 routing partials [b][144][256]
#define PART_SZ   (8*144*256)
#define R_OFF     (PART_OFF + PART_SZ)     // r  8*3*192
#define W1B_OFF   (R_OFF + 4608)           // 2*3*15*512 = 46080 ushort = 23040 float slots
#define W2B_OFF   (W1B_OFF + 23040)        // 36864 ushort

typedef __attribute__((ext_vector_type(8))) short short8_t;
typedef __attribute__((ext_vector_type(4))) float float4_t;

__device__ __forceinline__ unsigned short bf16_rne(float f){
  unsigned u = __float_as_uint(f);
  unsigned r = (u + 0x7FFFu + ((u>>16)&1u)) >> 16;
  return (unsigned short)r;
}
__device__ __forceinline__ float bf16_to_f(unsigned short h){
  return __uint_as_float(((unsigned)h) << 16);
}

// =====================================================================
// K_prep_filt: FUSED independent preprocessing (saves one launch).
//  blocks 0..35   : pack [w1 ; sp_w] and w2 into MFMA fragment order
//  blocks 36..611 : separable bicubic filter resize, stored in the
//                   COLUMN-OWNED spectral layout:
//                   filtP[s][m][cc][j] = float4( F[brev6(j)][fw(cc)],
//                                                F[brev6(j)+64][fw(cc)] )
//                   fw(cc) = (cc==64) ? 64 : brev6(cc).
// =====================================================================
__device__ __forceinline__ float cubicw(float tt){
  float t = fabsf(tt), t2=t*t, t3=t2*t;
  if (t <= 1.f) return 1.25f*t3 - 2.25f*t2 + 1.f;
  if (t < 2.f)  return -0.75f*t3 + 3.75f*t2 - 6.f*t + 3.f;
  return 0.f;
}

__global__ __launch_bounds__(256) void k_prep_filt(
    const float* __restrict__ w1, const float* __restrict__ sp_w,
    const float* __restrict__ w2,
    const float* __restrict__ cw0, const float* __restrict__ cw1,
    const float* __restrict__ cw2,
    unsigned short* __restrict__ W1B, unsigned short* __restrict__ W2B,
    float* __restrict__ filt)
{
  __shared__ float2 T[128][13];
  int bx = blockIdx.x;
  int t = threadIdx.x;

  if (bx < 36) {
    // ---- weight packing ----
    int tid = t + bx*256;
    int nthr = 256*36;
    for (int i = tid; i < 2*3*15*512; i += nthr) {
      int j = i & 7, l = (i>>3) & 63;
      int nt = (i>>9) % 15, kc = ((i>>9)/15) % 3, term = i / (3*15*512);
      int r = nt*16 + (l&15);
      int c = kc*32 + (l>>4)*8 + j;
      float v = (r < 192) ? w1[r*96 + c] : sp_w[(r-192)*96 + c];
      unsigned short hi = bf16_rne(v);
      W1B[i] = (term==0) ? hi : bf16_rne(v - bf16_to_f(hi));
    }
    for (int i = tid; i < 2*6*6*512; i += nthr) {
      int j = i & 7, l = (i>>3) & 63;
      int nt = (i>>9) % 6, kc = ((i>>9)/6) % 6, term = i / (6*6*512);
      int cp = nt*16 + (l&15);
      int m  = kc*32 + (l>>4)*8 + j;
      float v = w2[cp*192 + m];
      unsigned short hi = bf16_rne(v);
      W2B[i] = (term==0) ? hi : bf16_rne(v - bf16_to_f(hi));
    }
    return;
  }

  // ---- separable bicubic resize ----
  int fb = bx - 36;
  int s = fb / 192, m = fb - s*192;
  const float* cw = (s==0) ? cw0 : ((s==1) ? cw1 : cw2);
  const int SH = (s==0) ? 16 : ((s==1) ? 8 : 24);
  const int SW = (s==0) ? 9  : ((s==1) ? 4 : 13);

  // phase 1: h-resize into T[128][SW]
  for (int i = t; i < 128*SW; i += 256) {
    int fh = i / SW, iw = i - fh*SW;
    float sh = fh * (float)(SH-1) / 127.f;
    int fh0 = (int)floorf(sh);
    float2 acc = make_float2(0.f, 0.f);
    #pragma unroll
    for (int ka=0; ka<4; ++ka) {
      int kk = fh0-1+ka;
      float w = cubicw(sh - (float)kk);
      int ih = min(max(kk,0), SH-1);
      float2 v = *(const float2*)(cw + (size_t)((ih*SW + iw)*192 + m)*2);
      acc.x = fmaf(w, v.x, acc.x);
      acc.y = fmaf(w, v.y, acc.y);
    }
    T[fh][iw] = acc;
  }
  __syncthreads();

  // phase 2: w-resize, permuted to the column-owned float4 layout
  float4* outp = (float4*)filt + (size_t)(s*192+m)*4160;
  for (int i = t; i < 65*64; i += 256) {
    int cc = i >> 6, j = i & 63;
    int f  = __brev((unsigned)j) >> 26;                       // 0..63
    int fw = (cc == 64) ? 64 : (__brev((unsigned)cc) >> 26);  // natural fw
    float sw = fw * (float)(SW-1) / 64.f;
    int fw0 = (int)floorf(sw);
    float2 a0 = make_float2(0.f, 0.f);
    float2 a1 = make_float2(0.f, 0.f);
    #pragma unroll
    for (int kb=0; kb<4; ++kb) {
      int jj = fw0-1+kb;
      float w = cubicw(sw - (float)jj);
      int iw = min(max(jj,0), SW-1);
      float2 v0 = T[f][iw];
      float2 v1 = T[f+64][iw];
      a0.x = fmaf(w, v0.x, a0.x);
      a0.y = fmaf(w, v0.y, a0.y);
      a1.x = fmaf(w, v1.x, a1.x);
      a1.y = fmaf(w, v1.y, a1.y);
    }
    outp[i] = make_float4(a0.x, a0.y, a1.x, a1.y);
  }
}

// =====================================================================
// K_pw1 v2 (MFMA, fused routing stats) — byte-identical to round 12.
// =====================================================================
__global__ __launch_bounds__(256) void k_pw1(
    const float* __restrict__ x, const unsigned short* __restrict__ W1B,
    const float* __restrict__ soa_scale, const float* __restrict__ soa_bias,
    const float* __restrict__ bn_gamma, const float* __restrict__ bn_beta,
    const float* __restrict__ bn_mean, const float* __restrict__ bn_var,
    float* __restrict__ P, float* __restrict__ part)
{
  __shared__ float red[4][144];
  __shared__ float bnA_s[48], bnB_s[48];
  int t = threadIdx.x;
  int lane = t & 63, wv = t >> 6;
  if (t < 48) {
    float a = bn_gamma[t] * rsqrtf(bn_var[t] + 1e-5f);
    bnA_s[t] = a; bnB_s[t] = bn_beta[t] - bn_mean[t]*a;
  }
  int blk = blockIdx.x;
  int px0 = blk*64 + wv*16;
  int b = (blk*64) >> 14;
  int pxl = px0 & 16383;
  int g = lane >> 4;

  float4_t acc[15];
  #pragma unroll
  for (int nt=0; nt<15; ++nt) acc[nt] = (float4_t){0.f,0.f,0.f,0.f};

  #pragma unroll
  for (int kc=0; kc<3; ++kc) {
    const float* xp = x + (size_t)(px0 + (lane&15))*96 + kc*32 + g*8;
    float4 v0 = *(const float4*)xp;
    float4 v1 = *(const float4*)(xp+4);
    float vv[8] = {v0.x,v0.y,v0.z,v0.w, v1.x,v1.y,v1.z,v1.w};
    #pragma unroll
    for (int j=0;j<8;j++){
      float s = vv[j];
      s += __shfl_xor(s, 1);
      s += __shfl_xor(s, 2);
      s += __shfl_xor(s, 4);
      s += __shfl_xor(s, 8);
      if ((lane & 15) == 0) red[wv][kc*32 + g*8 + j] = s;
    }
    short8_t Bh, Bl;
    #pragma unroll
    for (int j=0;j<8;j++){
      unsigned short h = bf16_rne(vv[j]);
      Bh[j] = (short)h;
      Bl[j] = (short)bf16_rne(vv[j] - bf16_to_f(h));
    }
    const short8_t* a_hi = (const short8_t*)(W1B + (size_t)(0*3+kc)*15*512) + lane;
    const short8_t* a_lo = (const short8_t*)(W1B + (size_t)(1*3+kc)*15*512) + lane;
    #pragma unroll
    for (int nt=0; nt<15; ++nt) {
      short8_t Ah = a_hi[nt*64];
      short8_t Al = a_lo[nt*64];
      acc[nt] = __builtin_amdgcn_mfma_f32_16x16x32_bf16(Ah, Bh, acc[nt], 0,0,0);
      acc[nt] = __builtin_amdgcn_mfma_f32_16x16x32_bf16(Ah, Bl, acc[nt], 0,0,0);
      acc[nt] = __builtin_amdgcn_mfma_f32_16x16x32_bf16(Al, Bh, acc[nt], 0,0,0);
    }
  }
  float sc = soa_scale[0], bi = soa_bias[0];
  #pragma unroll
  for (int nt=0; nt<12; ++nt) {
    #pragma unroll
    for (int q=0;q<4;q++){
      float d = acc[nt][q];
      float v = fmaxf(d, 0.f);
      d = sc*v*v + bi;
      int mp = nt*16 + g*4 + q;
      P[(size_t)(b*192 + mp)*PSTR + pxl + (lane&15)] = d;
    }
  }
  #pragma unroll
  for (int tile=0; tile<3; ++tile) {
    #pragma unroll
    for (int q=0;q<4;q++){
      int s = tile*16 + g*4 + q;
      float y = acc[12+tile][q];
      float v = fmaxf(bnA_s[s]*y + bnB_s[s], 0.f);
      v += __shfl_xor(v, 1);
      v += __shfl_xor(v, 2);
      v += __shfl_xor(v, 4);
      v += __shfl_xor(v, 8);
      if ((lane & 15) == 0) red[wv][96 + s] = v;
    }
  }
  __syncthreads();
  if (t < 144) {
    float s = red[0][t] + red[1][t] + red[2][t] + red[3][t];
    part[((size_t)(b*144) + t)*256 + (blk & 255)] = s;
  }
}

// =====================================================================
// K_pw2 v1 (MFMA, direct) — byte-identical to round 12.
// =====================================================================
__global__ __launch_bounds__(256) void k_pw2(
    const float* __restrict__ P, const unsigned short* __restrict__ W2B,
    float* __restrict__ out)
{
  int t = threadIdx.x;
  int lane = t & 63, wv = t >> 6;
  int px0 = blockIdx.x*64 + wv*16;
  int b = px0 >> 14;
  int pxl = px0 & 16383;

  float4_t acc[6];
  #pragma unroll
  for (int nt=0; nt<6; ++nt) acc[nt] = (float4_t){0.f,0.f,0.f,0.f};

  #pragma unroll
  for (int kc=0; kc<6; ++kc) {
    const float* ap = P + (size_t)(b*192 + kc*32 + (lane>>4)*8)*PSTR + pxl + (lane&15);
    short8_t Ah, Al;
    #pragma unroll
    for (int j=0;j<8;j++){
      float v = ap[(size_t)j*PSTR];
      unsigned short h = bf16_rne(v);
      Ah[j] = (short)h;
      Al[j] = (short)bf16_rne(v - bf16_to_f(h));
    }
    const short8_t* b_hi = (const short8_t*)(W2B + (size_t)(0*6+kc)*6*512) + lane;
    const short8_t* b_lo = (const short8_t*)(W2B + (size_t)(1*6+kc)*6*512) + lane;
    #pragma unroll
    for (int nt=0; nt<6; ++nt) {
      short8_t Bh = b_hi[nt*64];
      short8_t Bl = b_lo[nt*64];
      acc[nt] = __builtin_amdgcn_mfma_f32_16x16x32_bf16(Ah, Bh, acc[nt], 0,0,0);
      acc[nt] = __builtin_amdgcn_mfma_f32_16x16x32_bf16(Ah, Bl, acc[nt], 0,0,0);
      acc[nt] = __builtin_amdgcn_mfma_f32_16x16x32_bf16(Al, Bh, acc[nt], 0,0,0);
    }
  }
  #pragma unroll
  for (int nt=0; nt<6; ++nt) {
    #pragma unroll
    for (int q=0;q<4;q++){
      int px = px0 + (lane>>4)*4 + q;
      out[(size_t)px*96 + nt*16 + (lane&15)] = acc[nt][q];
    }
  }
}

// =====================================================================
// K_route2 — byte-identical to round 12.
// =====================================================================
__global__ __launch_bounds__(256) void k_route2(
    const float* __restrict__ part,
    const float* __restrict__ fc1, const float* __restrict__ fc2,
    const float* __restrict__ mlp_scale, const float* __restrict__ mlp_bias,
    float* __restrict__ r_out)
{
  __shared__ float fused[144], hmid[36], rpre[576];
  int t = threadIdx.x, b = blockIdx.x;
  if (t < 144) {
    const float* pp = part + ((size_t)(b*144) + t)*256;
    float s = 0.f;
    for (int i = 0; i < 256; i += 4) {
      float4 v = *(const float4*)(pp + i);
      s += (v.x + v.y) + (v.z + v.w);
    }
    fused[t] = s * (1.f/16384.f);
  }
  __syncthreads();
  if (t < 36) {
    float a = 0.f;
    for (int i=0;i<144;i++) a = fmaf(fused[i], fc1[t*144+i], a);
    float rr = fmaxf(a, 0.f);
    hmid[t] = mlp_scale[0]*rr*rr + mlp_bias[0];
  }
  __syncthreads();
  for (int o = t; o < 576; o += 256) {
    float a = 0.f;
    for (int j=0;j<36;j++) a = fmaf(hmid[j], fc2[o*36+j], a);
    rpre[o] = a;
  }
  __syncthreads();
  if (t < 192) {
    float v0 = rpre[t], v1 = rpre[192+t], v2 = rpre[384+t];
    float mx = fmaxf(v0, fmaxf(v1, v2));
    float e0 = expf(v0-mx), e1 = expf(v1-mx), e2 = expf(v2-mx);
    float inv = 1.f/(e0+e1+e2);
    r_out[(b*3+0)*192+t] = e0*inv;
    r_out[(b*3+1)*192+t] = e1*inv;
    r_out[(b*3+2)*192+t] = e2*inv;
  }
}

// =====================================================================
// K_spectral v6: 2-BARRIER schedule via full column-wave-ownership.
//  - row phases unchanged (wave owns rows 16w..16w+15).
//  - col phases: wave w owns columns 8w..8w+7 for ALL column passes;
//    wave 0 additionally owns Nyquist col 64.  Lane map: cs = lane&7
//    (8 cols), u8 = lane>>3 (8 butterflies).  Bank-pair = (3p + col)
//    mod 16 lands 4 lanes/pair (b64 minimum) for every pass.
//  - fused multiply reads filtP[cc][j] float4 (128B-contiguous).
//  Barriers: bar1 rows->cols, bar2 cols->rows.  (was 9)
// =====================================================================
__device__ __forceinline__ float2 c_add(float2 a, float2 b){ return make_float2(a.x+b.x, a.y+b.y); }
__device__ __forceinline__ float2 c_sub(float2 a, float2 b){ return make_float2(a.x-b.x, a.y-b.y); }
__device__ __forceinline__ float2 c_mul(float2 a, float2 w){ return make_float2(a.x*w.x - a.y*w.y, a.x*w.y + a.y*w.x); }
__device__ __forceinline__ float2 c_mulc(float2 a, float2 w){ return make_float2(a.x*w.x + a.y*w.y, a.y*w.x - a.x*w.y); }

__device__ __forceinline__ void dif4(float2* S, const float2* TW,
    int a0, int a1, int a2, int a3, int t1, int t2, int t3)
{
  float2 x0=S[a0], x1=S[a1], x2=S[a2], x3=S[a3];
  float2 u = c_add(x0,x2), d0 = c_sub(x0,x2);
  float2 s = c_add(x1,x3), d1 = c_sub(x1,x3);
  float2 w = c_mul(d0, TW[t1]);
  float2 v = c_mul(d1, TW[t2]);
  float2 t3w = TW[t3];
  S[a0] = c_add(u,s);
  S[a1] = c_mul(c_sub(u,s), t3w);
  S[a2] = c_add(w,v);
  S[a3] = c_mul(c_sub(w,v), t3w);
}

__device__ __forceinline__ void dit4(float2* S, const float2* TW,
    int a0, int a1, int a2, int a3, int tA, int tB, int tC)
{
  float2 x0=S[a0], x1=S[a1], x2=S[a2], x3=S[a3];
  float2 wA = TW[tA];
  float2 x1t = c_mulc(x1, wA), x3t = c_mulc(x3, wA);
  float2 u = c_add(x0,x1t), v = c_sub(x0,x1t);
  float2 s = c_add(x2,x3t), w = c_sub(x2,x3t);
  float2 st = c_mulc(s, TW[tB]);
  float2 wt = c_mulc(w, TW[tC]);
  S[a0] = c_add(u, st);
  S[a2] = c_sub(u, st);
  S[a1] = c_add(v, wt);
  S[a3] = c_sub(v, wt);
}

__global__ __launch_bounds__(512, 4) void k_spectral(
    float* __restrict__ P, const float* __restrict__ filt, const float* __restrict__ r)
{
  __shared__ float2 S[128*LSTR];   // 68,608 B
  __shared__ float2 TW[64];
  int t = threadIdx.x;
  int lane = t & 63, wid = t >> 6;

  int i = blockIdx.x;
  int b = (i >> 3) & 7;
  int m = (i & 7) * 24 + (i >> 6);
  float* plane = P + ((size_t)b*192 + m) * PSTR;

  // every wave writes the full table (identical values); each wave's
  // reads are covered by its OWN in-order writes.
  {
    float ang = -6.283185307179586477f * (float)lane / 128.f;
    TW[lane] = make_float2(cosf(ang), sinf(ang));
  }

  // ---- load + even/odd pack (wave-owned rows 16w..16w+15) ----
  for (int it = 0; it < 8; ++it) {
    int row = 16*wid + (lane>>5) + 2*it;
    int j   = lane & 31;
    float4 v = ((const float4*)plane)[row*32 + j];
    int base = row*LSTR + 2*j;
    S[base]   = make_float2(v.x, v.y);
    S[base+1] = make_float2(v.z, v.w);
  }
  float r0 = r[(b*3+0)*192+m];
  float r1 = r[(b*3+1)*192+m];
  float r2 = r[(b*3+2)*192+m];

  // ---- forward rows: 3 radix-4 passes, wave-owned, NO barriers ----
  #pragma unroll
  for (int ps = 0; ps < 3; ++ps) {
    const int lh = 5 - 2*ps;               // 5,3,1
    const int h1 = 1 << lh, h2 = h1 >> 1;
    #pragma unroll
    for (int it = 0; it < 4; ++it) {
      int g = lane & 15;
      int row = 16*wid + (lane>>4) + 4*it;
      int k = g & (h2-1), blk = g >> (lh-1);
      int base = row*LSTR + blk*(2*h1) + k;
      dif4(S,TW, base, base+h2, base+h1, base+h1+h2,
           k << (6-lh), (k+h2) << (6-lh), k << (7-lh));
    }
  }

  // ---- unpack 65-bin half spectrum (row-fast lanes, NO barrier) ----
  for (int it = 0; it < 9; ++it) {
    int k   = (lane>>4) + 4*it;
    int row = 16*wid + (lane & 15);
    if (k <= 32) {
      int base = row*LSTR;
      if (k == 0) {
        float2 z = S[base];
        S[base]    = make_float2(z.x + z.y, 0.f);
        S[base+64] = make_float2(z.x - z.y, 0.f);
      } else {
        int a = __brev((unsigned)k) >> 26;
        int bidx = __brev((unsigned)(64-k)) >> 26;
        float2 A = S[base+a], B = S[base+bidx];
        float sr_ = 0.5f*(A.x+B.x), si_ = 0.5f*(A.y-B.y);
        float dr  = 0.5f*(A.x-B.x), di  = 0.5f*(A.y+B.y);
        float2 wq = TW[k];
        float tr = wq.x*di + wq.y*dr;
        float ti = -(wq.x*dr - wq.y*di);
        S[base+a]    = make_float2(sr_ + tr,  si_ + ti);
        S[base+bidx] = make_float2(sr_ - tr, -si_ + ti);
      }
    }
  }
  __syncthreads();                         // BAR1: rows -> cols

  int cs = lane & 7, u8 = lane >> 3;
  int mycol = 8*wid + cs;

  // ---- forward cols: 3 radix-4 DIF passes, column-owned, NO barriers ----
  #pragma unroll
  for (int ps = 0; ps < 3; ++ps) {
    const int lh = 6 - 2*ps;               // 6,4,2
    const int h1 = 1 << lh, h2 = h1 >> 1;
    #pragma unroll
    for (int it = 0; it < 4; ++it) {
      int bf = 8*it + u8;                  // butterfly 0..31
      int k = bf & (h2-1), blk = bf >> (lh-1);
      int p = blk*(2*h1) + k;
      dif4(S,TW, p*LSTR+mycol, (p+h2)*LSTR+mycol, (p+h1)*LSTR+mycol, (p+h1+h2)*LSTR+mycol,
           k << (6-lh), (k+h2) << (6-lh), k << (7-lh));
    }
    if (wid == 0 && lane < 32) {           // col 64 (Nyquist), wave 0
      int bf = lane;
      int k = bf & (h2-1), blk = bf >> (lh-1);
      int p = blk*(2*h1) + k;
      dif4(S,TW, p*LSTR+64, (p+h2)*LSTR+64, (p+h1)*LSTR+64, (p+h1+h2)*LSTR+64,
           k << (6-lh), (k+h2) << (6-lh), k << (7-lh));
    }
  }

  // ---- fused: final radix-2 (span 1) + routed multiply, column-owned ----
  {
    const float4* fb0 = (const float4*)filt + (size_t)(0*192+m)*4160;
    const float4* fb1 = (const float4*)filt + (size_t)(1*192+m)*4160;
    const float4* fb2 = (const float4*)filt + (size_t)(2*192+m)*4160;
    const float inv = 1.f/8192.f;
    #pragma unroll
    for (int it = 0; it < 8; ++it) {
      int j = 8*it + u8;                   // row-pair index 0..63
      int a0 = (2*j)*LSTR + mycol, a1 = a0 + LSTR;
      float2 uu = S[a0], vv = S[a1];
      float2 e = c_add(uu,vv), o = c_sub(uu,vv);   // freqs brev(j), brev(j)+64
      int fi = mycol*64 + j;
      float4 q0 = fb0[fi], q1 = fb1[fi], q2 = fb2[fi];
      float cr0 = (r0*q0.x + r1*q1.x + r2*q2.x) * inv;
      float ci0 = (r0*q0.y + r1*q1.y + r2*q2.y) * inv;
      float cr1 = (r0*q0.z + r1*q1.z + r2*q2.z) * inv;
      float ci1 = (r0*q0.w + r1*q1.w + r2*q2.w) * inv;
      S[a0] = make_float2(e.x*cr0 - e.y*ci0, e.x*ci0 + e.y*cr0);
      S[a1] = make_float2(o.x*cr1 - o.y*ci1, o.x*ci1 + o.y*cr1);
    }
    if (wid == 0) {                        // col 64, all 64 lanes
      int j = lane;
      int a0 = (2*j)*LSTR + 64, a1 = a0 + LSTR;
      float2 uu = S[a0], vv = S[a1];
      float2 e = c_add(uu,vv), o = c_sub(uu,vv);
      int fi = 64*64 + j;
      float4 q0 = fb0[fi], q1 = fb1[fi], q2 = fb2[fi];
      float cr0 = (r0*q0.x + r1*q1.x + r2*q2.x) * inv;
      float ci0 = (r0*q0.y + r1*q1.y + r2*q2.y) * inv;
      float cr1 = (r0*q0.z + r1*q1.z + r2*q2.z) * inv;
      float ci1 = (r0*q0.w + r1*q1.w + r2*q2.w) * inv;
      S[a0] = make_float2(e.x*cr0 - e.y*ci0, e.x*ci0 + e.y*cr0);
      S[a1] = make_float2(o.x*cr1 - o.y*ci1, o.x*ci1 + o.y*cr1);
    }
  }

  // ---- inverse cols: 3 radix-4 DIT passes, column-owned, NO barriers ----
  #pragma unroll
  for (int ps = 0; ps < 3; ++ps) {
    const int la = 2*ps;                   // 0,2,4
    const int h = 1 << la;
    #pragma unroll
    for (int it = 0; it < 4; ++it) {
      int bf = 8*it + u8;
      int k = bf & (h-1), blk = bf >> la;
      int p = blk*(4*h) + k;
      dit4(S,TW, p*LSTR+mycol, (p+h)*LSTR+mycol, (p+2*h)*LSTR+mycol, (p+3*h)*LSTR+mycol,
           k << (6-la), k << (5-la), (k+h) << (5-la));
    }
    if (wid == 0 && lane < 32) {           // col 64
      int bf = lane;
      int k = bf & (h-1), blk = bf >> la;
      int p = blk*(4*h) + k;
      dit4(S,TW, p*LSTR+64, (p+h)*LSTR+64, (p+2*h)*LSTR+64, (p+3*h)*LSTR+64,
           k << (6-la), k << (5-la), (k+h) << (5-la));
    }
  }
  // final radix-2 span 64, conj twiddle, column-owned
  #pragma unroll
  for (int it = 0; it < 8; ++it) {
    int k = 8*it + u8;
    int a0 = k*LSTR + mycol, a1 = a0 + 64*LSTR;
    float2 uu = S[a0], xv = S[a1];
    float2 xt = c_mulc(xv, TW[k]);
    S[a0] = c_add(uu,xt); S[a1] = c_sub(uu,xt);
  }
  if (wid == 0) {                          // col 64
    int k = lane;
    int a0 = k*LSTR + 64, a1 = a0 + 64*LSTR;
    float2 uu = S[a0], xv = S[a1];
    float2 xt = c_mulc(xv, TW[k]);
    S[a0] = c_add(uu,xt); S[a1] = c_sub(uu,xt);
  }
  __syncthreads();                         // BAR2: cols -> rows

  // ---- pack: drop imag at fw=0,64 (row-fast lanes, NO barrier) ----
  for (int it = 0; it < 9; ++it) {
    int k   = (lane>>4) + 4*it;
    int row = 16*wid + (lane & 15);
    if (k <= 32) {
      int base = row*LSTR;
      if (k == 0) {
        float ar = S[base].x;
        float cr = S[base+64].x;
        S[base] = make_float2(0.5f*(ar+cr), 0.5f*(ar-cr));
      } else {
        int a = __brev((unsigned)k) >> 26;
        int bidx = __brev((unsigned)(64-k)) >> 26;
        float2 A = S[base+a], B = S[base+bidx];
        float sr_ = 0.5f*(A.x+B.x), si_ = 0.5f*(A.y-B.y);
        float dr  = 0.5f*(A.x-B.x), di  = 0.5f*(A.y+B.y);
        float2 wq = TW[k];
        float tr2 = wq.y*dr - wq.x*di;
        float ti2 = wq.x*dr + wq.y*di;
        S[base+a]    = make_float2(sr_ + tr2,  si_ + ti2);
        S[base+bidx] = make_float2(sr_ - tr2, -si_ + ti2);
      }
    }
  }

  // ---- inverse rows: 3 DIT passes, wave-owned, NO barriers ----
  #pragma unroll
  for (int ps = 0; ps < 3; ++ps) {
    const int la = 2*ps;                   // 0,2,4
    const int h = 1 << la;
    #pragma unroll
    for (int it = 0; it < 4; ++it) {
      int g = lane & 15;
      int row = 16*wid + (lane>>4) + 4*it;
      int k = g & (h-1), blk = g >> la;
      int base = row*LSTR + blk*(4*h) + k;
      dit4(S,TW, base, base+h, base+2*h, base+3*h,
           k << (6-la), k << (5-la), (k+h) << (5-la));
    }
  }

  // ---- store (wave-owned rows, NO barrier) ----
  for (int it = 0; it < 8; ++it) {
    int row = 16*wid + (lane>>5) + 2*it;
    int j   = lane & 31;
    int base = row*LSTR + 2*j;
    float2 z0 = S[base], z1 = S[base+1];
    float4 v; v.x = z0.x; v.y = z0.y; v.z = z1.x; v.w = z1.y;
    ((float4*)plane)[row*32 + j] = v;
  }
}

// =====================================================================
extern "C" void kernel_launch(void* const* d_in, const int* in_sizes, int n_in,
                              void* d_out, int out_size, void* d_ws, size_t ws_size,
                              hipStream_t stream) {
  const float* x          = (const float*)d_in[0];
  const float* w1         = (const float*)d_in[1];
  const float* soa1_scale = (const float*)d_in[2];
  const float* soa1_bias  = (const float*)d_in[3];
  const float* cw0        = (const float*)d_in[4];
  const float* cw1        = (const float*)d_in[5];
  const float* cw2        = (const float*)d_in[6];
  const float* sp_w       = (const float*)d_in[7];
  const float* bn_gamma   = (const float*)d_in[8];
  const float* bn_beta    = (const float*)d_in[9];
  const float* bn_mean    = (const float*)d_in[10];
  const float* bn_var     = (const float*)d_in[11];
  const float* fc1        = (const float*)d_in[12];
  const float* mlp_scale  = (const float*)d_in[13];
  const float* mlp_bias   = (const float*)d_in[14];
  const float* fc2        = (const float*)d_in[15];
  const float* w2         = (const float*)d_in[16];
  float* out = (float*)d_out;

  float* ws   = (float*)d_ws;
  float* P    = ws + P_OFF;
  float* filt = ws + FILT_OFF;
  float* part = ws + PART_OFF;
  float* rbuf = ws + R_OFF;
  unsigned short* W1B = (unsigned short*)(ws + W1B_OFF);
  unsigned short* W2B = (unsigned short*)(ws + W2B_OFF);

  k_prep_filt<<<612, 256, 0, stream>>>(w1, sp_w, w2, cw0, cw1, cw2, W1B, W2B, filt);
  k_pw1      <<<2048,256, 0, stream>>>(x, W1B, soa1_scale, soa1_bias,
                                       bn_gamma, bn_beta, bn_mean, bn_var,
                                       P, part);
  k_route2   <<<8,   256, 0, stream>>>(part, fc1, fc2, mlp_scale, mlp_bias, rbuf);
  k_spectral <<<1536,512, 0, stream>>>(P, filt, rbuf);
  k_pw2      <<<2048,256, 0, stream>>>(P, W2B, out);
}